// Round 3
// baseline (167.022 us; speedup 1.0000x reference)
//
#include <hip/hip_runtime.h>
#include <math.h>

#define NCH 96      // B*C = 32*3
#define HH 512
#define WW 512
#define OH 502      // valid output rows/cols (512 - 10)
#define STRIP 32    // output rows per block
#define NSTRIP 16   // 502 = 15*32 + 22
#define NT 256      // threads per block, 2 columns each

struct Win { float w[11]; };

__device__ __forceinline__ float ssim_px(float m1, float m2, float ms, float mp) {
    const float C1v = 1e-4f;   // (0.01*1.0)^2
    const float C2v = 9e-4f;   // (0.03*1.0)^2
    float mu12  = m1 * m2;
    float musum = fmaf(m1, m1, m2 * m2);              // mu1^2 + mu2^2
    float num = fmaf(2.f, mp - mu12, C2v) * fmaf(2.f, mu12, C1v);
    float den = ((ms - musum) + C2v) * (musum + C1v); // > 0 always
    return num * __builtin_amdgcn_rcpf(den);
}

// horizontal polyphase: output col 2t uses E[t..t+5] (w0,w2,..,w10) and O[t..t+4] (w1,..,w9)
//                       output col 2t+1 uses O[t..t+5] (w0,w2,..,w10) and E[t+1..t+5] (w1,..,w9)
#define HB_A(f) (w0*e0.f + w1*o0.f + w2*e1.f + w3*o1.f + w4*e2.f + w5*o2.f \
               + w6*e3.f + w7*o3.f + w8*e4.f + w9*o4.f + w10*e5.f)
#define HB_B(f) (w0*o0.f + w1*e1.f + w2*o1.f + w3*e2.f + w4*o2.f + w5*e3.f \
               + w6*o3.f + w7*e4.f + w8*o4.f + w9*e5.f + w10*o5.f)

// 11-tap vertical blur: taps 0..9 from slots S0..S9 (static!), tap 10 = n
#define VB(q,S0,S1,S2,S3,S4,S5,S6,S7,S8,S9,n) \
  fmaf(w0,q[S0],fmaf(w1,q[S1],fmaf(w2,q[S2],fmaf(w3,q[S3],fmaf(w4,q[S4], \
  fmaf(w5,q[S5],fmaf(w6,q[S6],fmaf(w7,q[S7],fmaf(w8,q[S8],fmaf(w9,q[S9],w10*(n)))))))))))

#define SH1(q) do { q[0]=q[1];q[1]=q[2];q[2]=q[3];q[3]=q[4];q[4]=q[5]; \
                    q[5]=q[6];q[6]=q[7];q[7]=q[8];q[8]=q[9]; } while(0)

// One output row. RR = output row index (uniform across block). Taps 0..9 come
// from slots S0..S9 of the shift registers; tap 10 from held row (hx,hy).
// If DOSHIFT: shift-by-1 then store held at slot 9; else store held at SST.
#define ROW_CORE(RR,S0,S1,S2,S3,S4,S5,S6,S7,S8,S9,SST,DOSHIFT) do {             \
    const float nax = fmaf(hx.x,0.5f,0.5f), nbx = fmaf(hx.y,0.5f,0.5f);         \
    const float nay = fmaf(hy.x,0.5f,0.5f), nby = fmaf(hy.y,0.5f,0.5f);         \
    const float nas = fmaf(nax,nax,nay*nay), nap = nax*nay;                     \
    const float nbs = fmaf(nbx,nbx,nby*nby), nbp = nbx*nby;                     \
    float vxA = VB(Axv,S0,S1,S2,S3,S4,S5,S6,S7,S8,S9,nax);                      \
    float vyA = VB(Ayv,S0,S1,S2,S3,S4,S5,S6,S7,S8,S9,nay);                      \
    float vsA = VB(Asv,S0,S1,S2,S3,S4,S5,S6,S7,S8,S9,nas);                      \
    float vpA = VB(Apv,S0,S1,S2,S3,S4,S5,S6,S7,S8,S9,nap);                      \
    float vxB = VB(Bxv,S0,S1,S2,S3,S4,S5,S6,S7,S8,S9,nbx);                      \
    float vyB = VB(Byv,S0,S1,S2,S3,S4,S5,S6,S7,S8,S9,nby);                      \
    float vsB = VB(Bsv,S0,S1,S2,S3,S4,S5,S6,S7,S8,S9,nbs);                      \
    float vpB = VB(Bpv,S0,S1,S2,S3,S4,S5,S6,S7,S8,S9,nbp);                      \
    const int buf_ = (RR) & 1;                                                  \
    Eb[buf_][t] = make_float4(vxA,vyA,vsA,vpA);                                 \
    Ob[buf_][t] = make_float4(vxB,vyB,vsB,vpB);                                 \
    if (DOSHIFT) { SH1(Axv);SH1(Ayv);SH1(Asv);SH1(Apv);                         \
                   SH1(Bxv);SH1(Byv);SH1(Bsv);SH1(Bpv);                         \
      Axv[9]=nax; Ayv[9]=nay; Asv[9]=nas; Apv[9]=nap;                           \
      Bxv[9]=nbx; Byv[9]=nby; Bsv[9]=nbs; Bpv[9]=nbp;                           \
    } else {                                                                    \
      Axv[SST]=nax; Ayv[SST]=nay; Asv[SST]=nas; Apv[SST]=nap;                   \
      Bxv[SST]=nbx; Byv[SST]=nby; Bsv[SST]=nbs; Bpv[SST]=nbp;                   \
    }                                                                           \
    { const int g_ = min(r0+(RR)+11, HH-1);                                     \
      hx = *(const float2*)(xcol + (size_t)g_*WW);                              \
      hy = *(const float2*)(ycol + (size_t)g_*WW); }                            \
    __syncthreads();                                                            \
    if (t <= 250) {                                                             \
        const float4* Ep = Eb[buf_];                                            \
        const float4* Op = Ob[buf_];                                            \
        float4 e0 = Ep[t],     e1 = Ep[t + 1], e2 = Ep[t + 2];                  \
        float4 e3 = Ep[t + 3], e4 = Ep[t + 4], e5 = Ep[t + 5];                  \
        float4 o0 = Op[t],     o1 = Op[t + 1], o2 = Op[t + 2];                  \
        float4 o3 = Op[t + 3], o4 = Op[t + 4], o5 = Op[t + 5];                  \
        float A1 = HB_A(x), A2 = HB_A(y), As = HB_A(z), Ap = HB_A(w);           \
        float B1 = HB_B(x), B2 = HB_B(y), Bs = HB_B(z), Bp = HB_B(w);           \
        acc += ssim_px(A1, A2, As, Ap);                                         \
        acc += ssim_px(B1, B2, Bs, Bp);                                         \
    }                                                                           \
} while(0)

__global__ __launch_bounds__(NT, 4)
void ssim_main(const float* __restrict__ X, const float* __restrict__ Y,
               float* __restrict__ partial, Win win) {
    __shared__ float4 Eb[2][256];   // even columns, vblur row (vx,vy,vs,vp)
    __shared__ float4 Ob[2][256];   // odd columns
    __shared__ float red[4];

    const int b     = blockIdx.x;
    const int ch    = b >> 4;         // / NSTRIP
    const int strip = b & 15;
    const int r0    = strip * STRIP;
    const int rows  = min(STRIP, OH - r0);
    const int t     = threadIdx.x;

    const float w0 = win.w[0], w1 = win.w[1], w2 = win.w[2], w3 = win.w[3];
    const float w4 = win.w[4], w5 = win.w[5], w6 = win.w[6], w7 = win.w[7];
    const float w8 = win.w[8], w9 = win.w[9], w10 = win.w[10];

    const size_t choff = (size_t)ch * (HH * WW);
    const float* xcol = X + choff + 2 * t;   // column-pair base
    const float* ycol = Y + choff + 2 * t;

    // 10-slot shift registers: normalized x, y, x^2+y^2, x*y for even (A) and
    // odd (B) columns. All indices static (rotated phases / explicit movs).
    float Axv[10], Ayv[10], Asv[10], Apv[10];
    float Bxv[10], Byv[10], Bsv[10], Bpv[10];

    #pragma unroll
    for (int i = 0; i < 10; ++i) {
        float2 xv = *(const float2*)(xcol + (size_t)(r0 + i) * WW);
        float2 yv = *(const float2*)(ycol + (size_t)(r0 + i) * WW);
        float x0 = fmaf(xv.x, 0.5f, 0.5f), x1 = fmaf(xv.y, 0.5f, 0.5f);
        float y0 = fmaf(yv.x, 0.5f, 0.5f), y1 = fmaf(yv.y, 0.5f, 0.5f);
        Axv[i] = x0; Ayv[i] = y0; Asv[i] = fmaf(x0,x0,y0*y0); Apv[i] = x0*y0;
        Bxv[i] = x1; Byv[i] = y1; Bsv[i] = fmaf(x1,x1,y1*y1); Bpv[i] = x1*y1;
    }
    // held raw row r0+10
    float2 hx = *(const float2*)(xcol + (size_t)(r0 + 10) * WW);
    float2 hy = *(const float2*)(ycol + (size_t)(r0 + 10) * WW);

    float acc = 0.f;
    int r = 0;

    // main body: groups of 10 rows, statically rotated slots (zero shift movs)
    while (r + 10 <= rows) {
        ROW_CORE(r+0, 0,1,2,3,4,5,6,7,8,9, 0, 0);
        ROW_CORE(r+1, 1,2,3,4,5,6,7,8,9,0, 1, 0);
        ROW_CORE(r+2, 2,3,4,5,6,7,8,9,0,1, 2, 0);
        ROW_CORE(r+3, 3,4,5,6,7,8,9,0,1,2, 3, 0);
        ROW_CORE(r+4, 4,5,6,7,8,9,0,1,2,3, 4, 0);
        ROW_CORE(r+5, 5,6,7,8,9,0,1,2,3,4, 5, 0);
        ROW_CORE(r+6, 6,7,8,9,0,1,2,3,4,5, 6, 0);
        ROW_CORE(r+7, 7,8,9,0,1,2,3,4,5,6, 7, 0);
        ROW_CORE(r+8, 8,9,0,1,2,3,4,5,6,7, 8, 0);
        ROW_CORE(r+9, 9,0,1,2,3,4,5,6,7,8, 9, 0);
        r += 10;
    }
    // remainder (<= 2 rows per strip): explicit-mov shift, slots stay 0..9
    for (; r < rows; ++r) {
        ROW_CORE(r, 0,1,2,3,4,5,6,7,8,9, 9, 1);
    }

    // block reduction -> one partial per block (no atomics: deterministic)
    #pragma unroll
    for (int m = 1; m < 64; m <<= 1) acc += __shfl_xor(acc, m, 64);
    __syncthreads();
    if ((t & 63) == 0) red[t >> 6] = acc;
    __syncthreads();
    if (t == 0) partial[b] = (red[0] + red[1]) + (red[2] + red[3]);
}

__global__ __launch_bounds__(128)
void ssim_final(const float* __restrict__ partial, float* __restrict__ out) {
    const int t = threadIdx.x;  // 128 threads
    float v = 0.f;
    if (t < NCH) {
        float s = 0.f;
        #pragma unroll
        for (int i = 0; i < NSTRIP; ++i) s += partial[t * NSTRIP + i];
        s *= (1.f / (502.f * 502.f));   // per-channel spatial mean
        v = fmaxf(s, 0.f);              // relu (nonnegative_ssim)
    }
    #pragma unroll
    for (int m = 1; m < 64; m <<= 1) v += __shfl_xor(v, m, 64);
    __shared__ float r2[2];
    if ((t & 63) == 0) r2[t >> 6] = v;
    __syncthreads();
    if (t == 0) out[0] = 1.f - (r2[0] + r2[1]) * (1.f / (float)NCH);
}

extern "C" void kernel_launch(void* const* d_in, const int* in_sizes, int n_in,
                              void* d_out, int out_size, void* d_ws, size_t ws_size,
                              hipStream_t stream) {
    const float* X = (const float*)d_in[0];
    const float* Y = (const float*)d_in[1];
    float* out = (float*)d_out;
    float* partial = (float*)d_ws;   // NCH*NSTRIP = 1536 floats

    Win win;
    double g[11], sum = 0.0;
    for (int i = 0; i < 11; ++i) {
        double c = (double)(i - 5);
        g[i] = exp(-(c * c) / (2.0 * 1.5 * 1.5));
        sum += g[i];
    }
    for (int i = 0; i < 11; ++i) win.w[i] = (float)(g[i] / sum);

    ssim_main<<<NCH * NSTRIP, NT, 0, stream>>>(X, Y, partial, win);
    ssim_final<<<1, 128, 0, stream>>>(partial, out);
}

// Round 4
// 129.513 us; speedup vs baseline: 1.2896x; 1.2896x over previous
//
#include <hip/hip_runtime.h>
#include <math.h>

#define NCH 96      // B*C = 32*3
#define HH 512
#define WW 512
#define OH 502      // valid output rows/cols (512 - 10)
#define STRIP 32    // output rows per block
#define NSTRIP 16   // 502 = 15*32 + 22
#define NT 256      // threads per block, 2 columns each

struct Win { float w[11]; };

__device__ __forceinline__ float ssim_px(float m1, float m2, float ms, float mp) {
    const float C1v = 1e-4f;   // (0.01*1.0)^2
    const float C2v = 9e-4f;   // (0.03*1.0)^2
    float mu12  = m1 * m2;
    float musum = fmaf(m1, m1, m2 * m2);              // mu1^2 + mu2^2
    float num = fmaf(2.f, mp - mu12, C2v) * fmaf(2.f, mu12, C1v);
    float den = ((ms - musum) + C2v) * (musum + C1v); // > 0 always
    return num * __builtin_amdgcn_rcpf(den);
}

// horizontal polyphase: output col 2t uses E[t..t+5] (w0,w2,..,w10) and O[t..t+4] (w1,..,w9)
//                       output col 2t+1 uses O[t..t+5] (w0,w2,..,w10) and E[t+1..t+5] (w1,..,w9)
#define HB_A(f) (w0*e0.f + w1*o0.f + w2*e1.f + w3*o1.f + w4*e2.f + w5*o2.f \
               + w6*e3.f + w7*o3.f + w8*e4.f + w9*o4.f + w10*e5.f)
#define HB_B(f) (w0*o0.f + w1*e1.f + w2*o1.f + w3*e2.f + w4*o2.f + w5*e3.f \
               + w6*o3.f + w7*e4.f + w8*o4.f + w9*e5.f + w10*o5.f)

__global__ __launch_bounds__(NT, 3)
void ssim_main(const float* __restrict__ X, const float* __restrict__ Y,
               float* __restrict__ partial, Win win) {
    __shared__ float4 Eb[2][256];   // even columns, vblur row (vx,vy,vs,vp)
    __shared__ float4 Ob[2][256];   // odd columns
    __shared__ float red[4];

    const int b     = blockIdx.x;
    const int ch    = b >> 4;         // / NSTRIP
    const int strip = b & 15;
    const int r0    = strip * STRIP;
    const int rows  = min(STRIP, OH - r0);
    const int t     = threadIdx.x;

    const size_t choff = (size_t)ch * (HH * WW);
    const float* xcol = X + choff + 2 * t;   // column-pair base
    const float* ycol = Y + choff + 2 * t;

    // 10-slot shift registers of NORMALIZED values, all indices static.
    // Slot i holds row r+i for current output row r. Tap 10 comes from `held`.
    float axv[10], ayv[10], bxv[10], byv[10];

    #pragma unroll
    for (int i = 0; i < 10; ++i) {
        float2 xv = *(const float2*)(xcol + (size_t)(r0 + i) * WW);
        float2 yv = *(const float2*)(ycol + (size_t)(r0 + i) * WW);
        axv[i] = fmaf(xv.x, 0.5f, 0.5f); bxv[i] = fmaf(xv.y, 0.5f, 0.5f);
        ayv[i] = fmaf(yv.x, 0.5f, 0.5f); byv[i] = fmaf(yv.y, 0.5f, 0.5f);
    }
    // held raw row r0+10
    float2 hx = *(const float2*)(xcol + (size_t)(r0 + 10) * WW);
    float2 hy = *(const float2*)(ycol + (size_t)(r0 + 10) * WW);

    float acc = 0.f;

    for (int r = 0; r < rows; ++r) {
        const int buf = r & 1;
        // normalize held row (tap 10)
        const float nax = fmaf(hx.x, 0.5f, 0.5f), nbx = fmaf(hx.y, 0.5f, 0.5f);
        const float nay = fmaf(hy.x, 0.5f, 0.5f), nby = fmaf(hy.y, 0.5f, 0.5f);

        // vertical blur; s = x*x+y*y and p = x*y computed on the fly
        float vxA, vyA, vsA, vpA, vxB, vyB, vsB, vpB;
        {
            const float wk = win.w[10];
            vxA = wk * nax; vyA = wk * nay;
            vsA = wk * fmaf(nax, nax, nay * nay); vpA = wk * (nax * nay);
            vxB = wk * nbx; vyB = wk * nby;
            vsB = wk * fmaf(nbx, nbx, nby * nby); vpB = wk * (nbx * nby);
        }
        #pragma unroll
        for (int k = 0; k < 10; ++k) {
            const float wk = win.w[k];
            const float xa = axv[k], ya = ayv[k], xb = bxv[k], yb = byv[k];
            vxA = fmaf(wk, xa, vxA); vyA = fmaf(wk, ya, vyA);
            vsA = fmaf(wk, fmaf(xa, xa, ya * ya), vsA); vpA = fmaf(wk, xa * ya, vpA);
            vxB = fmaf(wk, xb, vxB); vyB = fmaf(wk, yb, vyB);
            vsB = fmaf(wk, fmaf(xb, xb, yb * yb), vsB); vpB = fmaf(wk, xb * yb, vpB);
        }
        Eb[buf][t] = make_float4(vxA, vyA, vsA, vpA);
        Ob[buf][t] = make_float4(vxB, vyB, vsB, vpB);

        // shift by one row; append normalized held
        #pragma unroll
        for (int k = 0; k < 9; ++k) {
            axv[k] = axv[k + 1]; ayv[k] = ayv[k + 1];
            bxv[k] = bxv[k + 1]; byv[k] = byv[k + 1];
        }
        axv[9] = nax; ayv[9] = nay; bxv[9] = nbx; byv[9] = nby;

        // prefetch next raw row (clamped; clamped value is never consumed)
        {
            const int g = min(r0 + r + 11, HH - 1);
            hx = *(const float2*)(xcol + (size_t)g * WW);
            hy = *(const float2*)(ycol + (size_t)g * WW);
        }

        __syncthreads();
        // horizontal blur + ssim for output cols 2t, 2t+1 (only 0..501 valid)
        if (t <= 250) {
            const float4* Ep = Eb[buf];
            const float4* Op = Ob[buf];
            float4 e0 = Ep[t],     e1 = Ep[t + 1], e2 = Ep[t + 2];
            float4 e3 = Ep[t + 3], e4 = Ep[t + 4], e5 = Ep[t + 5];
            float4 o0 = Op[t],     o1 = Op[t + 1], o2 = Op[t + 2];
            float4 o3 = Op[t + 3], o4 = Op[t + 4], o5 = Op[t + 5];
            const float w0 = win.w[0], w1 = win.w[1], w2 = win.w[2], w3 = win.w[3];
            const float w4 = win.w[4], w5 = win.w[5], w6 = win.w[6], w7 = win.w[7];
            const float w8 = win.w[8], w9 = win.w[9], w10 = win.w[10];
            float A1 = HB_A(x), A2 = HB_A(y), As = HB_A(z), Ap = HB_A(w);
            float B1 = HB_B(x), B2 = HB_B(y), Bs = HB_B(z), Bp = HB_B(w);
            acc += ssim_px(A1, A2, As, Ap);
            acc += ssim_px(B1, B2, Bs, Bp);
        }
    }

    // block reduction -> one partial per block (no atomics: deterministic)
    #pragma unroll
    for (int m = 1; m < 64; m <<= 1) acc += __shfl_xor(acc, m, 64);
    __syncthreads();
    if ((t & 63) == 0) red[t >> 6] = acc;
    __syncthreads();
    if (t == 0) partial[b] = (red[0] + red[1]) + (red[2] + red[3]);
}

__global__ __launch_bounds__(128)
void ssim_final(const float* __restrict__ partial, float* __restrict__ out) {
    const int t = threadIdx.x;  // 128 threads
    float v = 0.f;
    if (t < NCH) {
        float s = 0.f;
        #pragma unroll
        for (int i = 0; i < NSTRIP; ++i) s += partial[t * NSTRIP + i];
        s *= (1.f / (502.f * 502.f));   // per-channel spatial mean
        v = fmaxf(s, 0.f);              // relu (nonnegative_ssim)
    }
    #pragma unroll
    for (int m = 1; m < 64; m <<= 1) v += __shfl_xor(v, m, 64);
    __shared__ float r2[2];
    if ((t & 63) == 0) r2[t >> 6] = v;
    __syncthreads();
    if (t == 0) out[0] = 1.f - (r2[0] + r2[1]) * (1.f / (float)NCH);
}

extern "C" void kernel_launch(void* const* d_in, const int* in_sizes, int n_in,
                              void* d_out, int out_size, void* d_ws, size_t ws_size,
                              hipStream_t stream) {
    const float* X = (const float*)d_in[0];
    const float* Y = (const float*)d_in[1];
    float* out = (float*)d_out;
    float* partial = (float*)d_ws;   // NCH*NSTRIP = 1536 floats

    Win win;
    double g[11], sum = 0.0;
    for (int i = 0; i < 11; ++i) {
        double c = (double)(i - 5);
        g[i] = exp(-(c * c) / (2.0 * 1.5 * 1.5));
        sum += g[i];
    }
    for (int i = 0; i < 11; ++i) win.w[i] = (float)(g[i] / sum);

    ssim_main<<<NCH * NSTRIP, NT, 0, stream>>>(X, Y, partial, win);
    ssim_final<<<1, 128, 0, stream>>>(partial, out);
}

// Round 5
// 86.805 us; speedup vs baseline: 1.9241x; 1.4920x over previous
//
#include <hip/hip_runtime.h>
#include <math.h>

typedef float f32x2 __attribute__((ext_vector_type(2)));

#define NCH 96      // B*C = 32*3
#define HH 512
#define WW 512
#define OH 502      // valid output rows/cols (512 - 10)
#define STRIP 32    // output rows per block
#define NSTRIP 16
#define NT 256      // threads per block, 2 columns each

struct Win { float w[11]; };

__device__ __forceinline__ f32x2 pkfma(f32x2 a, f32x2 b, f32x2 c) {
    return __builtin_elementwise_fma(a, b, c);
}

__device__ __forceinline__ float ssim_px(float m1, float m2, float ms, float mp) {
    const float C1v = 1e-4f;   // (0.01*1.0)^2
    const float C2v = 9e-4f;   // (0.03*1.0)^2
    float mu12  = m1 * m2;
    float musum = fmaf(m1, m1, m2 * m2);              // mu1^2 + mu2^2
    float num = fmaf(2.f, mp - mu12, C2v) * fmaf(2.f, mu12, C1v);
    float den = ((ms - musum) + C2v) * (musum + C1v); // > 0 always
    return num * __builtin_amdgcn_rcpf(den);
}

// packed 11-tap horizontal blur chain (taps T0..T10, weights Wv[0..10])
#define HB(T0,T1,T2,T3,T4,T5,T6,T7,T8,T9,T10) \
  pkfma(T10, Wv[10], pkfma(T9, Wv[9], pkfma(T8, Wv[8], pkfma(T7, Wv[7], \
  pkfma(T6, Wv[6], pkfma(T5, Wv[5], pkfma(T4, Wv[4], pkfma(T3, Wv[3], \
  pkfma(T2, Wv[2], pkfma(T1, Wv[1], T0 * Wv[0]))))))))))

__global__ __launch_bounds__(NT, 4)
void ssim_main(const float* __restrict__ X, const float* __restrict__ Y,
               float* __restrict__ partial, Win win) {
    __shared__ float4 Eb[2][256];   // even columns, vblur row (vx,vy,vs,vp)
    __shared__ float4 Ob[2][256];   // odd columns
    __shared__ float red[4];

    const int b     = blockIdx.x;
    const int ch    = b >> 4;         // / NSTRIP
    const int strip = b & 15;
    const int r0    = strip * STRIP;
    const int rows  = min(STRIP, OH - r0);
    const int t     = threadIdx.x;

    f32x2 Wv[11];
    #pragma unroll
    for (int i = 0; i < 11; ++i) Wv[i] = (f32x2){win.w[i], win.w[i]};
    const f32x2 h2 = {0.5f, 0.5f};

    const size_t choff = (size_t)ch * (HH * WW);
    const float* xcol = X + choff + 2 * t;   // column-pair base
    const float* ycol = Y + choff + 2 * t;

    // 10-slot shift registers of NORMALIZED (even,odd) packed values.
    f32x2 xs[10], ys[10];

    #pragma unroll
    for (int i = 0; i < 10; ++i) {
        f32x2 xv = *(const f32x2*)(xcol + (size_t)(r0 + i) * WW);
        f32x2 yv = *(const f32x2*)(ycol + (size_t)(r0 + i) * WW);
        xs[i] = pkfma(xv, h2, h2);
        ys[i] = pkfma(yv, h2, h2);
    }
    // held raw row r0+10
    f32x2 hx = *(const f32x2*)(xcol + (size_t)(r0 + 10) * WW);
    f32x2 hy = *(const f32x2*)(ycol + (size_t)(r0 + 10) * WW);

    float acc = 0.f;

    for (int r = 0; r < rows; ++r) {
        const int buf = r & 1;
        // normalize held row (tap 10); s,p on the fly
        f32x2 nx = pkfma(hx, h2, h2);
        f32x2 ny = pkfma(hy, h2, h2);
        f32x2 ns = pkfma(ny, ny, nx * nx);
        f32x2 np = nx * ny;

        f32x2 vx = nx * Wv[10], vy = ny * Wv[10];
        f32x2 vs = ns * Wv[10], vp = np * Wv[10];
        #pragma unroll
        for (int k = 0; k < 10; ++k) {
            f32x2 xk = xs[k], yk = ys[k];
            f32x2 sk = pkfma(yk, yk, xk * xk);
            f32x2 pk = xk * yk;
            vx = pkfma(xk, Wv[k], vx);
            vy = pkfma(yk, Wv[k], vy);
            vs = pkfma(sk, Wv[k], vs);
            vp = pkfma(pk, Wv[k], vp);
        }
        Eb[buf][t] = make_float4(vx.x, vy.x, vs.x, vp.x);
        Ob[buf][t] = make_float4(vx.y, vy.y, vs.y, vp.y);

        // shift by one row; append normalized held
        #pragma unroll
        for (int k = 0; k < 9; ++k) { xs[k] = xs[k + 1]; ys[k] = ys[k + 1]; }
        xs[9] = nx; ys[9] = ny;

        // prefetch next raw row (clamped; clamped value is never consumed)
        {
            const int g = min(r0 + r + 11, HH - 1);
            hx = *(const f32x2*)(xcol + (size_t)g * WW);
            hy = *(const f32x2*)(ycol + (size_t)g * WW);
        }

        __syncthreads();
        // horizontal blur + ssim for output cols 2t, 2t+1 (only 0..501 valid)
        if (t <= 250) {
            const float4* Ep = Eb[buf];
            const float4* Op = Ob[buf];
            float4 e0 = Ep[t],     e1 = Ep[t + 1], e2 = Ep[t + 2];
            float4 e3 = Ep[t + 3], e4 = Ep[t + 4], e5 = Ep[t + 5];
            float4 o0 = Op[t],     o1 = Op[t + 1], o2 = Op[t + 2];
            float4 o3 = Op[t + 3], o4 = Op[t + 4], o5 = Op[t + 5];
            // m-halves (mu1,mu2) and s-halves (msum, mprod) — free extractions
            f32x2 e0m = {e0.x, e0.y}, e1m = {e1.x, e1.y}, e2m = {e2.x, e2.y};
            f32x2 e3m = {e3.x, e3.y}, e4m = {e4.x, e4.y}, e5m = {e5.x, e5.y};
            f32x2 o0m = {o0.x, o0.y}, o1m = {o1.x, o1.y}, o2m = {o2.x, o2.y};
            f32x2 o3m = {o3.x, o3.y}, o4m = {o4.x, o4.y}, o5m = {o5.x, o5.y};
            f32x2 e0s = {e0.z, e0.w}, e1s = {e1.z, e1.w}, e2s = {e2.z, e2.w};
            f32x2 e3s = {e3.z, e3.w}, e4s = {e4.z, e4.w}, e5s = {e5.z, e5.w};
            f32x2 o0s = {o0.z, o0.w}, o1s = {o1.z, o1.w}, o2s = {o2.z, o2.w};
            f32x2 o3s = {o3.z, o3.w}, o4s = {o4.z, o4.w}, o5s = {o5.z, o5.w};

            f32x2 Am = HB(e0m,o0m,e1m,o1m,e2m,o2m,e3m,o3m,e4m,o4m,e5m);
            f32x2 As = HB(e0s,o0s,e1s,o1s,e2s,o2s,e3s,o3s,e4s,o4s,e5s);
            f32x2 Bm = HB(o0m,e1m,o1m,e2m,o2m,e3m,o3m,e4m,o4m,e5m,o5m);
            f32x2 Bs = HB(o0s,e1s,o1s,e2s,o2s,e3s,o3s,e4s,o4s,e5s,o5s);

            acc += ssim_px(Am.x, Am.y, As.x, As.y);
            acc += ssim_px(Bm.x, Bm.y, Bs.x, Bs.y);
        }
    }

    // block reduction -> one partial per block (no atomics: deterministic)
    #pragma unroll
    for (int m = 1; m < 64; m <<= 1) acc += __shfl_xor(acc, m, 64);
    __syncthreads();
    if ((t & 63) == 0) red[t >> 6] = acc;
    __syncthreads();
    if (t == 0) partial[b] = (red[0] + red[1]) + (red[2] + red[3]);
}

__global__ __launch_bounds__(128)
void ssim_final(const float* __restrict__ partial, float* __restrict__ out) {
    const int t = threadIdx.x;  // 128 threads
    float v = 0.f;
    if (t < NCH) {
        float s = 0.f;
        #pragma unroll
        for (int i = 0; i < NSTRIP; ++i) s += partial[t * NSTRIP + i];
        s *= (1.f / (502.f * 502.f));   // per-channel spatial mean
        v = fmaxf(s, 0.f);              // relu (nonnegative_ssim)
    }
    #pragma unroll
    for (int m = 1; m < 64; m <<= 1) v += __shfl_xor(v, m, 64);
    __shared__ float r2[2];
    if ((t & 63) == 0) r2[t >> 6] = v;
    __syncthreads();
    if (t == 0) out[0] = 1.f - (r2[0] + r2[1]) * (1.f / (float)NCH);
}

extern "C" void kernel_launch(void* const* d_in, const int* in_sizes, int n_in,
                              void* d_out, int out_size, void* d_ws, size_t ws_size,
                              hipStream_t stream) {
    const float* X = (const float*)d_in[0];
    const float* Y = (const float*)d_in[1];
    float* out = (float*)d_out;
    float* partial = (float*)d_ws;   // NCH*NSTRIP = 1536 floats

    Win win;
    double g[11], sum = 0.0;
    for (int i = 0; i < 11; ++i) {
        double c = (double)(i - 5);
        g[i] = exp(-(c * c) / (2.0 * 1.5 * 1.5));
        sum += g[i];
    }
    for (int i = 0; i < 11; ++i) win.w[i] = (float)(g[i] / sum);

    ssim_main<<<NCH * NSTRIP, NT, 0, stream>>>(X, Y, partial, win);
    ssim_final<<<1, 128, 0, stream>>>(partial, out);
}

// Round 6
// 78.174 us; speedup vs baseline: 2.1366x; 1.1104x over previous
//
#include <hip/hip_runtime.h>
#include <math.h>

typedef float f32x2 __attribute__((ext_vector_type(2)));

#define NCH 96      // B*C = 32*3
#define HH 512
#define WW 512
#define OH 502      // valid output rows/cols (512 - 10)
#define STRIP 32    // output rows per block (always even; last strip = 22, even)
#define NSTRIP 16
#define NT 256      // threads per block, 2 columns each

struct Win { float w[11]; };

__device__ __forceinline__ f32x2 pkfma(f32x2 a, f32x2 b, f32x2 c) {
    return __builtin_elementwise_fma(a, b, c);
}
__device__ __forceinline__ f32x2 pkfmas(f32x2 a, float s, f32x2 c) {
    f32x2 sv = {s, s};
    return __builtin_elementwise_fma(a, sv, c);
}
__device__ __forceinline__ f32x2 pkmuls(f32x2 a, float s) {
    f32x2 sv = {s, s};
    return a * sv;
}

__device__ __forceinline__ float ssim_px(float m1, float m2, float ms, float mp) {
    const float C1v = 1e-4f;   // (0.01*1.0)^2
    const float C2v = 9e-4f;   // (0.03*1.0)^2
    float mu12  = m1 * m2;
    float musum = fmaf(m1, m1, m2 * m2);              // mu1^2 + mu2^2
    float num = fmaf(2.f, mp - mu12, C2v) * fmaf(2.f, mu12, C1v);
    float den = ((ms - musum) + C2v) * (musum + C1v); // > 0 always
    return num * __builtin_amdgcn_rcpf(den);
}

// packed 11-tap horizontal blur chain (taps T0..T10, scalar weights w0..w10)
#define HB(T0,T1,T2,T3,T4,T5,T6,T7,T8,T9,T10) \
  pkfmas(T10, w10, pkfmas(T9, w9, pkfmas(T8, w8, pkfmas(T7, w7, \
  pkfmas(T6, w6, pkfmas(T5, w5, pkfmas(T4, w4, pkfmas(T3, w3, \
  pkfmas(T2, w2, pkfmas(T1, w1, pkmuls(T0, w0)))))))))))

__global__ __launch_bounds__(NT, 4)
void ssim_main(const float* __restrict__ X, const float* __restrict__ Y,
               float* __restrict__ partial, Win win) {
    // M = (mu1_e, mu2_e, mu1_o, mu2_o); S = (ms_e, mp_e, ms_o, mp_o)
    __shared__ float4 Mb[2][2][256];   // [set][row01][colpair]
    __shared__ float4 Sb[2][2][256];
    __shared__ float red[4];

    const int b     = blockIdx.x;
    const int ch    = b >> 4;         // / NSTRIP
    const int strip = b & 15;
    const int r0    = strip * STRIP;
    const int rows  = min(STRIP, OH - r0);   // 32 or 22 (even)
    const int t     = threadIdx.x;

    const float w0 = win.w[0], w1 = win.w[1], w2 = win.w[2], w3 = win.w[3];
    const float w4 = win.w[4], w5 = win.w[5], w6 = win.w[6], w7 = win.w[7];
    const float w8 = win.w[8], w9 = win.w[9], w10 = win.w[10];
    const f32x2 h2 = {0.5f, 0.5f};

    const size_t choff = (size_t)ch * (HH * WW);
    const float* xcol = X + choff + 2 * t;   // column-pair base
    const float* ycol = Y + choff + 2 * t;

    // 10-slot shift ring of NORMALIZED (even,odd) packed values.
    f32x2 xs[10], ys[10];
    #pragma unroll
    for (int i = 0; i < 10; ++i) {
        f32x2 xv = *(const f32x2*)(xcol + (size_t)(r0 + i) * WW);
        f32x2 yv = *(const f32x2*)(ycol + (size_t)(r0 + i) * WW);
        xs[i] = pkfma(xv, h2, h2);
        ys[i] = pkfma(yv, h2, h2);
    }
    // held raw rows r0+10, r0+11
    f32x2 hx1 = *(const f32x2*)(xcol + (size_t)(r0 + 10) * WW);
    f32x2 hy1 = *(const f32x2*)(ycol + (size_t)(r0 + 10) * WW);
    f32x2 hx2 = *(const f32x2*)(xcol + (size_t)(r0 + 11) * WW);
    f32x2 hy2 = *(const f32x2*)(ycol + (size_t)(r0 + 11) * WW);

    float acc = 0.f;

    for (int r = 0; r < rows; r += 2) {
        const int set = (r >> 1) & 1;
        // normalize held rows; s,p on the fly
        f32x2 n1x = pkfma(hx1, h2, h2), n1y = pkfma(hy1, h2, h2);
        f32x2 n2x = pkfma(hx2, h2, h2), n2y = pkfma(hy2, h2, h2);
        f32x2 n1s = pkfma(n1y, n1y, n1x * n1x), n1p = n1x * n1y;
        f32x2 n2s = pkfma(n2y, n2y, n2x * n2x), n2p = n2x * n2y;

        // vblur row A = r   : w[k] over ring[0..9] (rows r..r+9) + w10*n1
        //       row B = r+1 : w[k-1] over ring[1..9] + w9*n1 + w10*n2
        f32x2 uAx = pkmuls(n1x, w10), uAy = pkmuls(n1y, w10);
        f32x2 uAs = pkmuls(n1s, w10), uAp = pkmuls(n1p, w10);
        f32x2 uBx = pkfmas(n1x, w9, pkmuls(n2x, w10));
        f32x2 uBy = pkfmas(n1y, w9, pkmuls(n2y, w10));
        f32x2 uBs = pkfmas(n1s, w9, pkmuls(n2s, w10));
        f32x2 uBp = pkfmas(n1p, w9, pkmuls(n2p, w10));
        #pragma unroll
        for (int k = 0; k < 10; ++k) {
            const float wk = win.w[k];
            f32x2 qx = xs[k], qy = ys[k];
            f32x2 qs = pkfma(qy, qy, qx * qx), qp = qx * qy;   // shared by both rows
            uAx = pkfmas(qx, wk, uAx); uAy = pkfmas(qy, wk, uAy);
            uAs = pkfmas(qs, wk, uAs); uAp = pkfmas(qp, wk, uAp);
            if (k >= 1) {
                const float wk1 = win.w[k - 1];
                uBx = pkfmas(qx, wk1, uBx); uBy = pkfmas(qy, wk1, uBy);
                uBs = pkfmas(qs, wk1, uBs); uBp = pkfmas(qp, wk1, uBp);
            }
        }
        Mb[set][0][t] = make_float4(uAx.x, uAy.x, uAx.y, uAy.y);
        Sb[set][0][t] = make_float4(uAs.x, uAp.x, uAs.y, uAp.y);
        Mb[set][1][t] = make_float4(uBx.x, uBy.x, uBx.y, uBy.y);
        Sb[set][1][t] = make_float4(uBs.x, uBp.x, uBs.y, uBp.y);

        // shift ring by 2; append normalized held rows
        #pragma unroll
        for (int k = 0; k < 8; ++k) { xs[k] = xs[k + 2]; ys[k] = ys[k + 2]; }
        xs[8] = n1x; ys[8] = n1y; xs[9] = n2x; ys[9] = n2y;

        // prefetch rows r0+r+12, r0+r+13 (clamped; clamped never consumed)
        {
            const int g1 = min(r0 + r + 12, HH - 1);
            const int g2 = min(r0 + r + 13, HH - 1);
            hx1 = *(const f32x2*)(xcol + (size_t)g1 * WW);
            hy1 = *(const f32x2*)(ycol + (size_t)g1 * WW);
            hx2 = *(const f32x2*)(xcol + (size_t)g2 * WW);
            hy2 = *(const f32x2*)(ycol + (size_t)g2 * WW);
        }

        __syncthreads();
        // horizontal blur + ssim for output cols 2t, 2t+1 of both rows
        if (t <= 250) {
            #pragma unroll
            for (int rr = 0; rr < 2; ++rr) {
                const float4* Mp = Mb[set][rr];
                const float4* Sp = Sb[set][rr];
                float4 m0 = Mp[t],     m1 = Mp[t + 1], m2 = Mp[t + 2];
                float4 m3 = Mp[t + 3], m4 = Mp[t + 4], m5 = Mp[t + 5];
                float4 s0 = Sp[t],     s1 = Sp[t + 1], s2 = Sp[t + 2];
                float4 s3 = Sp[t + 3], s4 = Sp[t + 4], s5 = Sp[t + 5];
                f32x2 e0m = {m0.x, m0.y}, o0m = {m0.z, m0.w};
                f32x2 e1m = {m1.x, m1.y}, o1m = {m1.z, m1.w};
                f32x2 e2m = {m2.x, m2.y}, o2m = {m2.z, m2.w};
                f32x2 e3m = {m3.x, m3.y}, o3m = {m3.z, m3.w};
                f32x2 e4m = {m4.x, m4.y}, o4m = {m4.z, m4.w};
                f32x2 e5m = {m5.x, m5.y}, o5m = {m5.z, m5.w};
                f32x2 e0s = {s0.x, s0.y}, o0s = {s0.z, s0.w};
                f32x2 e1s = {s1.x, s1.y}, o1s = {s1.z, s1.w};
                f32x2 e2s = {s2.x, s2.y}, o2s = {s2.z, s2.w};
                f32x2 e3s = {s3.x, s3.y}, o3s = {s3.z, s3.w};
                f32x2 e4s = {s4.x, s4.y}, o4s = {s4.z, s4.w};
                f32x2 e5s = {s5.x, s5.y}, o5s = {s5.z, s5.w};

                f32x2 Am = HB(e0m,o0m,e1m,o1m,e2m,o2m,e3m,o3m,e4m,o4m,e5m);
                f32x2 As = HB(e0s,o0s,e1s,o1s,e2s,o2s,e3s,o3s,e4s,o4s,e5s);
                f32x2 Bm = HB(o0m,e1m,o1m,e2m,o2m,e3m,o3m,e4m,o4m,e5m,o5m);
                f32x2 Bs = HB(o0s,e1s,o1s,e2s,o2s,e3s,o3s,e4s,o4s,e5s,o5s);

                acc += ssim_px(Am.x, Am.y, As.x, As.y);
                acc += ssim_px(Bm.x, Bm.y, Bs.x, Bs.y);
            }
        }
    }

    // block reduction -> one partial per block (no atomics: deterministic)
    #pragma unroll
    for (int m = 1; m < 64; m <<= 1) acc += __shfl_xor(acc, m, 64);
    __syncthreads();
    if ((t & 63) == 0) red[t >> 6] = acc;
    __syncthreads();
    if (t == 0) partial[b] = (red[0] + red[1]) + (red[2] + red[3]);
}

__global__ __launch_bounds__(128)
void ssim_final(const float* __restrict__ partial, float* __restrict__ out) {
    const int t = threadIdx.x;  // 128 threads
    float v = 0.f;
    if (t < NCH) {
        float s = 0.f;
        #pragma unroll
        for (int i = 0; i < NSTRIP; ++i) s += partial[t * NSTRIP + i];
        s *= (1.f / (502.f * 502.f));   // per-channel spatial mean
        v = fmaxf(s, 0.f);              // relu (nonnegative_ssim)
    }
    #pragma unroll
    for (int m = 1; m < 64; m <<= 1) v += __shfl_xor(v, m, 64);
    __shared__ float r2[2];
    if ((t & 63) == 0) r2[t >> 6] = v;
    __syncthreads();
    if (t == 0) out[0] = 1.f - (r2[0] + r2[1]) * (1.f / (float)NCH);
}

extern "C" void kernel_launch(void* const* d_in, const int* in_sizes, int n_in,
                              void* d_out, int out_size, void* d_ws, size_t ws_size,
                              hipStream_t stream) {
    const float* X = (const float*)d_in[0];
    const float* Y = (const float*)d_in[1];
    float* out = (float*)d_out;
    float* partial = (float*)d_ws;   // NCH*NSTRIP = 1536 floats

    Win win;
    double g[11], sum = 0.0;
    for (int i = 0; i < 11; ++i) {
        double c = (double)(i - 5);
        g[i] = exp(-(c * c) / (2.0 * 1.5 * 1.5));
        sum += g[i];
    }
    for (int i = 0; i < 11; ++i) win.w[i] = (float)(g[i] / sum);

    ssim_main<<<NCH * NSTRIP, NT, 0, stream>>>(X, Y, partial, win);
    ssim_final<<<1, 128, 0, stream>>>(partial, out);
}

// Round 7
// 77.738 us; speedup vs baseline: 2.1485x; 1.0056x over previous
//
#include <hip/hip_runtime.h>
#include <math.h>

typedef float f32x2 __attribute__((ext_vector_type(2)));

#define NCH 96      // B*C = 32*3
#define HH 512
#define WW 512
#define OH 502      // valid output rows/cols (512 - 10)
#define STRIP 32    // output rows per block (last strip = 22, even)
#define NSTRIP 16
#define NT 256      // threads per block, 2 columns each

struct Win { float w[11]; };

__device__ __forceinline__ f32x2 pkfma(f32x2 a, f32x2 b, f32x2 c) {
    return __builtin_elementwise_fma(a, b, c);
}
__device__ __forceinline__ f32x2 pkfmas(f32x2 a, float s, f32x2 c) {
    f32x2 sv = {s, s};
    return __builtin_elementwise_fma(a, sv, c);
}
__device__ __forceinline__ f32x2 pkmuls(f32x2 a, float s) {
    f32x2 sv = {s, s};
    return a * sv;
}

// packed SSIM for two pixels: mu1,mu2,ms,mp hold (pixelA, pixelB)
__device__ __forceinline__ float ssim_px2(f32x2 mu1, f32x2 mu2, f32x2 ms, f32x2 mp) {
    const f32x2 C1v = {1e-4f, 1e-4f};   // (0.01)^2
    const f32x2 C2v = {9e-4f, 9e-4f};   // (0.03)^2
    const f32x2 two = {2.f, 2.f};
    f32x2 mu12  = mu1 * mu2;
    f32x2 musum = pkfma(mu1, mu1, mu2 * mu2);
    f32x2 num = pkfma(two, mp - mu12, C2v) * pkfma(two, mu12, C1v);
    f32x2 den = ((ms - musum) + C2v) * (musum + C1v); // > 0 always
    float ra = __builtin_amdgcn_rcpf(den.x);
    float rb = __builtin_amdgcn_rcpf(den.y);
    return fmaf(num.x, ra, num.y * rb);
}

// packed 11-tap horizontal blur chain (taps T0..T10, scalar weights w0..w10)
#define HB(T0,T1,T2,T3,T4,T5,T6,T7,T8,T9,T10) \
  pkfmas(T10, w10, pkfmas(T9, w9, pkfmas(T8, w8, pkfmas(T7, w7, \
  pkfmas(T6, w6, pkfmas(T5, w5, pkfmas(T4, w4, pkfmas(T3, w3, \
  pkfmas(T2, w2, pkfmas(T1, w1, pkmuls(T0, w0)))))))))))

__global__ __launch_bounds__(NT, 4)
void ssim_main(const float* __restrict__ X, const float* __restrict__ Y,
               float* __restrict__ partial, Win win) {
    // M = (mu1_e, mu2_e, mu1_o, mu2_o); S = (ms_e, mp_e, ms_o, mp_o)
    __shared__ float4 Mb[2][2][256];   // [set][row01][colpair]
    __shared__ float4 Sb[2][2][256];
    __shared__ float red[4];

    const int b     = blockIdx.x;
    const int ch    = b >> 4;         // / NSTRIP
    const int strip = b & 15;
    const int r0    = strip * STRIP;
    const int rows  = min(STRIP, OH - r0);   // 32 or 22 (even)
    const int t     = threadIdx.x;

    const float w0 = win.w[0], w1 = win.w[1], w2 = win.w[2], w3 = win.w[3];
    const float w4 = win.w[4], w5 = win.w[5], w6 = win.w[6], w7 = win.w[7];
    const float w8 = win.w[8], w9 = win.w[9], w10 = win.w[10];
    const f32x2 h2 = {0.5f, 0.5f};

    const size_t choff = (size_t)ch * (HH * WW);
    const float* xcol = X + choff + 2 * t;   // column-pair base
    const float* ycol = Y + choff + 2 * t;

    // 10-slot shift ring of NORMALIZED (even,odd) packed values.
    f32x2 xs[10], ys[10];
    #pragma unroll
    for (int i = 0; i < 10; ++i) {
        f32x2 xv = *(const f32x2*)(xcol + (size_t)(r0 + i) * WW);
        f32x2 yv = *(const f32x2*)(ycol + (size_t)(r0 + i) * WW);
        xs[i] = pkfma(xv, h2, h2);
        ys[i] = pkfma(yv, h2, h2);
    }
    // held raw rows r0+10, r0+11
    f32x2 hx1 = *(const f32x2*)(xcol + (size_t)(r0 + 10) * WW);
    f32x2 hy1 = *(const f32x2*)(ycol + (size_t)(r0 + 10) * WW);
    f32x2 hx2 = *(const f32x2*)(xcol + (size_t)(r0 + 11) * WW);
    f32x2 hy2 = *(const f32x2*)(ycol + (size_t)(r0 + 11) * WW);

    float acc = 0.f;

    for (int r = 0; r < rows; r += 2) {
        const int set = (r >> 1) & 1;
        // normalize held rows (consume prefetch); s,p on the fly
        f32x2 n1x = pkfma(hx1, h2, h2), n1y = pkfma(hy1, h2, h2);
        f32x2 n2x = pkfma(hx2, h2, h2), n2y = pkfma(hy2, h2, h2);
        f32x2 n1s = pkfma(n1y, n1y, n1x * n1x), n1p = n1x * n1y;
        f32x2 n2s = pkfma(n2y, n2y, n2x * n2x), n2p = n2x * n2y;

        // vblur row A = r   : w[k] over ring[0..9] (rows r..r+9) + w10*n1
        //       row B = r+1 : w[k-1] over ring[1..9] + w9*n1 + w10*n2
        f32x2 uAx = pkmuls(n1x, w10), uAy = pkmuls(n1y, w10);
        f32x2 uAs = pkmuls(n1s, w10), uAp = pkmuls(n1p, w10);
        f32x2 uBx = pkfmas(n1x, w9, pkmuls(n2x, w10));
        f32x2 uBy = pkfmas(n1y, w9, pkmuls(n2y, w10));
        f32x2 uBs = pkfmas(n1s, w9, pkmuls(n2s, w10));
        f32x2 uBp = pkfmas(n1p, w9, pkmuls(n2p, w10));
        #pragma unroll
        for (int k = 0; k < 10; ++k) {
            const float wk = win.w[k];
            f32x2 qx = xs[k], qy = ys[k];
            f32x2 qs = pkfma(qy, qy, qx * qx), qp = qx * qy;   // shared by both rows
            uAx = pkfmas(qx, wk, uAx); uAy = pkfmas(qy, wk, uAy);
            uAs = pkfmas(qs, wk, uAs); uAp = pkfmas(qp, wk, uAp);
            if (k >= 1) {
                const float wk1 = win.w[k - 1];
                uBx = pkfmas(qx, wk1, uBx); uBy = pkfmas(qy, wk1, uBy);
                uBs = pkfmas(qs, wk1, uBs); uBp = pkfmas(qp, wk1, uBp);
            }
        }
        Mb[set][0][t] = make_float4(uAx.x, uAy.x, uAx.y, uAy.y);
        Sb[set][0][t] = make_float4(uAs.x, uAp.x, uAs.y, uAp.y);
        Mb[set][1][t] = make_float4(uBx.x, uBy.x, uBx.y, uBy.y);
        Sb[set][1][t] = make_float4(uBs.x, uBp.x, uBs.y, uBp.y);

        // shift ring by 2; append normalized held rows
        #pragma unroll
        for (int k = 0; k < 8; ++k) { xs[k] = xs[k + 2]; ys[k] = ys[k + 2]; }
        xs[8] = n1x; ys[8] = n1y; xs[9] = n2x; ys[9] = n2y;

        __syncthreads();

        // issue prefetch AFTER the barrier: loads stay in flight under this
        // iteration's hblur + next iteration's normalize/vblur, instead of
        // being drained by the barrier's vmcnt(0). (T14 issue-early split.)
        {
            const int g1 = min(r0 + r + 12, HH - 1);
            const int g2 = min(r0 + r + 13, HH - 1);
            hx1 = *(const f32x2*)(xcol + (size_t)g1 * WW);
            hy1 = *(const f32x2*)(ycol + (size_t)g1 * WW);
            hx2 = *(const f32x2*)(xcol + (size_t)g2 * WW);
            hy2 = *(const f32x2*)(ycol + (size_t)g2 * WW);
        }

        // horizontal blur + ssim for output cols 2t, 2t+1 of both rows
        if (t <= 250) {
            #pragma unroll
            for (int rr = 0; rr < 2; ++rr) {
                const float4* Mp = Mb[set][rr];
                const float4* Sp = Sb[set][rr];
                float4 m0 = Mp[t],     m1 = Mp[t + 1], m2 = Mp[t + 2];
                float4 m3 = Mp[t + 3], m4 = Mp[t + 4], m5 = Mp[t + 5];
                float4 s0 = Sp[t],     s1 = Sp[t + 1], s2 = Sp[t + 2];
                float4 s3 = Sp[t + 3], s4 = Sp[t + 4], s5 = Sp[t + 5];
                f32x2 e0m = {m0.x, m0.y}, o0m = {m0.z, m0.w};
                f32x2 e1m = {m1.x, m1.y}, o1m = {m1.z, m1.w};
                f32x2 e2m = {m2.x, m2.y}, o2m = {m2.z, m2.w};
                f32x2 e3m = {m3.x, m3.y}, o3m = {m3.z, m3.w};
                f32x2 e4m = {m4.x, m4.y}, o4m = {m4.z, m4.w};
                f32x2 e5m = {m5.x, m5.y}, o5m = {m5.z, m5.w};
                f32x2 e0s = {s0.x, s0.y}, o0s = {s0.z, s0.w};
                f32x2 e1s = {s1.x, s1.y}, o1s = {s1.z, s1.w};
                f32x2 e2s = {s2.x, s2.y}, o2s = {s2.z, s2.w};
                f32x2 e3s = {s3.x, s3.y}, o3s = {s3.z, s3.w};
                f32x2 e4s = {s4.x, s4.y}, o4s = {s4.z, s4.w};
                f32x2 e5s = {s5.x, s5.y}, o5s = {s5.z, s5.w};

                f32x2 Am = HB(e0m,o0m,e1m,o1m,e2m,o2m,e3m,o3m,e4m,o4m,e5m);
                f32x2 As = HB(e0s,o0s,e1s,o1s,e2s,o2s,e3s,o3s,e4s,o4s,e5s);
                f32x2 Bm = HB(o0m,e1m,o1m,e2m,o2m,e3m,o3m,e4m,o4m,e5m,o5m);
                f32x2 Bs = HB(o0s,e1s,o1s,e2s,o2s,e3s,o3s,e4s,o4s,e5s,o5s);

                // pack (A,B): mu1={Am.x,Bm.x}, mu2={Am.y,Bm.y}, ms={As.x,Bs.x}, mp={As.y,Bs.y}
                f32x2 mu1 = {Am.x, Bm.x}, mu2 = {Am.y, Bm.y};
                f32x2 msv = {As.x, Bs.x}, mpv = {As.y, Bs.y};
                acc += ssim_px2(mu1, mu2, msv, mpv);
            }
        }
    }

    // block reduction -> one partial per block (no atomics: deterministic)
    #pragma unroll
    for (int m = 1; m < 64; m <<= 1) acc += __shfl_xor(acc, m, 64);
    __syncthreads();
    if ((t & 63) == 0) red[t >> 6] = acc;
    __syncthreads();
    if (t == 0) partial[b] = (red[0] + red[1]) + (red[2] + red[3]);
}

__global__ __launch_bounds__(128)
void ssim_final(const float* __restrict__ partial, float* __restrict__ out) {
    const int t = threadIdx.x;  // 128 threads
    float v = 0.f;
    if (t < NCH) {
        float s = 0.f;
        #pragma unroll
        for (int i = 0; i < NSTRIP; ++i) s += partial[t * NSTRIP + i];
        s *= (1.f / (502.f * 502.f));   // per-channel spatial mean
        v = fmaxf(s, 0.f);              // relu (nonnegative_ssim)
    }
    #pragma unroll
    for (int m = 1; m < 64; m <<= 1) v += __shfl_xor(v, m, 64);
    __shared__ float r2[2];
    if ((t & 63) == 0) r2[t >> 6] = v;
    __syncthreads();
    if (t == 0) out[0] = 1.f - (r2[0] + r2[1]) * (1.f / (float)NCH);
}

extern "C" void kernel_launch(void* const* d_in, const int* in_sizes, int n_in,
                              void* d_out, int out_size, void* d_ws, size_t ws_size,
                              hipStream_t stream) {
    const float* X = (const float*)d_in[0];
    const float* Y = (const float*)d_in[1];
    float* out = (float*)d_out;
    float* partial = (float*)d_ws;   // NCH*NSTRIP = 1536 floats

    Win win;
    double g[11], sum = 0.0;
    for (int i = 0; i < 11; ++i) {
        double c = (double)(i - 5);
        g[i] = exp(-(c * c) / (2.0 * 1.5 * 1.5));
        sum += g[i];
    }
    for (int i = 0; i < 11; ++i) win.w[i] = (float)(g[i] / sum);

    ssim_main<<<NCH * NSTRIP, NT, 0, stream>>>(X, Y, partial, win);
    ssim_final<<<1, 128, 0, stream>>>(partial, out);
}